// Round 2
// 619.030 us; speedup vs baseline: 1.0085x; 1.0085x over previous
//
#include <hip/hip_runtime.h>
#include <math.h>

#define BATCH 16384
#define LATENT 16

// ---------------------------------------------------------------------------
// FFM forward:
//   fm[b]  = sum_{i<j} dot( mean_s E_i[j-1][x_i[b,s]], mean_s E_j[i][x_j[b,s]] )
//   lin[b] = relu( sum_i mean_s(L_i[x_i[b,s]]) * Wd[i] + bd )
//   out[b] = sigmoid(lin[b] + fm[b])
//
// Layout E: 16 lanes per batch element = 4 latent-quads (q) x 4 seq-phases (h).
//   lane t = h*4 + q. Each lane loads float4 (16B) per E row -> dwordx4,
//   1 KB per wave per load instruction (vs 256B with scalar dword loads).
//   SEQ>1 fields split the sequence across h (s = 4k+h) and cross-reduce the
//   partial sums with __shfl_xor(4/8, width 16). SEQ=1 fields load uniformly
//   across h (hardware merges the replicated addresses).
//   Pair dot products are consumed incrementally after each field's load so
//   the register allocator can retire each v_ij early (peak ~10 live f4 vecs
//   instead of 30 -> VGPR <= 128, 4 waves/SIMD).
// ---------------------------------------------------------------------------

typedef float f4 __attribute__((ext_vector_type(4)));

__device__ __forceinline__ float phsum(float v) {
    v += __shfl_xor(v, 4, 16);
    v += __shfl_xor(v, 8, 16);
    return v;
}
__device__ __forceinline__ f4 phsum4(f4 a) {
    a.x = phsum(a.x);
    a.y = phsum(a.y);
    a.z = phsum(a.z);
    a.w = phsum(a.w);
    return a;
}

// SEQ > 1: phases h=0..3 split the sequence, then reduce across h.
template<int SEQ, int DIM>
__device__ __forceinline__ void field_split(const int* __restrict__ x,
                                            const float* __restrict__ E,
                                            const float* __restrict__ L,
                                            int b, int voq, int h,
                                            f4 v[5], float& lmean)
{
    // 5 slot base pointers -> SGPRs; loads use shared 32-bit voffset.
    const float* __restrict__ e0 = E;
    const float* __restrict__ e1 = E + (size_t)DIM * LATENT;
    const float* __restrict__ e2 = E + (size_t)DIM * LATENT * 2;
    const float* __restrict__ e3 = E + (size_t)DIM * LATENT * 3;
    const float* __restrict__ e4 = E + (size_t)DIM * LATENT * 4;
    const int* __restrict__ xb = x + b * SEQ + h;

    f4 a0 = 0.f, a1 = 0.f, a2 = 0.f, a3 = 0.f, a4 = 0.f;
    float ls = 0.f;
    constexpr int K    = SEQ / 4;
    constexpr int TAIL = SEQ & 3;
#pragma unroll 4
    for (int k = 0; k < K; ++k) {
        const int idx = xb[4 * k];
        const int off = idx * LATENT + voq;   // < 2^31 for all DIMs
        a0 += *(const f4*)(e0 + off);
        a1 += *(const f4*)(e1 + off);
        a2 += *(const f4*)(e2 + off);
        a3 += *(const f4*)(e3 + off);
        a4 += *(const f4*)(e4 + off);
        ls += L[idx];
    }
    if constexpr (TAIL > 0) {
        if (h < TAIL) {
            const int idx = xb[4 * K];
            const int off = idx * LATENT + voq;
            a0 += *(const f4*)(e0 + off);
            a1 += *(const f4*)(e1 + off);
            a2 += *(const f4*)(e2 + off);
            a3 += *(const f4*)(e3 + off);
            a4 += *(const f4*)(e4 + off);
            ls += L[idx];
        }
    }
    const float inv = 1.0f / (float)SEQ;
    v[0] = phsum4(a0) * inv;
    v[1] = phsum4(a1) * inv;
    v[2] = phsum4(a2) * inv;
    v[3] = phsum4(a3) * inv;
    v[4] = phsum4(a4) * inv;
    lmean = phsum(ls) * inv;
}

// SEQ == 1: all phase groups load the same row (merged by the coalescer);
// values are already uniform across h, no reduction needed.
template<int DIM>
__device__ __forceinline__ void field_one(const int* __restrict__ x,
                                          const float* __restrict__ E,
                                          const float* __restrict__ L,
                                          int b, int voq,
                                          f4 v[5], float& lmean)
{
    const int idx = x[b];
    const int off = idx * LATENT + voq;
    v[0] = *(const f4*)(E + off);
    v[1] = *(const f4*)(E + (size_t)DIM * LATENT     + off);
    v[2] = *(const f4*)(E + (size_t)DIM * LATENT * 2 + off);
    v[3] = *(const f4*)(E + (size_t)DIM * LATENT * 3 + off);
    v[4] = *(const f4*)(E + (size_t)DIM * LATENT * 4 + off);
    lmean = L[idx];
}

__global__ __launch_bounds__(256) void ffm_kernel(
    const int* __restrict__ x0, const int* __restrict__ x1,
    const int* __restrict__ x2, const int* __restrict__ x3,
    const int* __restrict__ x4, const int* __restrict__ x5,
    const float* __restrict__ E0, const float* __restrict__ E1,
    const float* __restrict__ E2, const float* __restrict__ E3,
    const float* __restrict__ E4, const float* __restrict__ E5,
    const float* __restrict__ L0, const float* __restrict__ L1,
    const float* __restrict__ L2, const float* __restrict__ L3,
    const float* __restrict__ L4, const float* __restrict__ L5,
    const float* __restrict__ Wd, const float* __restrict__ bd,
    float* __restrict__ out)
{
    const int tid = blockIdx.x * blockDim.x + threadIdx.x;
    const int b   = tid >> 4;      // batch element (16 lanes each)
    const int t   = tid & 15;
    const int q   = t & 3;         // latent quad (4 floats)
    const int h   = t >> 2;        // sequence phase
    const int voq = q * 4;         // float offset of this quad within a row

    f4 v0[5], v1[5], v2[5], v3[5], v4[5], v5[5];
    float f0m, f1m, f2m, f3m, f4m, f5m;
    f4 fmv = 0.f;

    // Big gather fields first; fold each pair product in as soon as both
    // operands exist so dead vectors retire early.
    field_split<50, 500000>(x2, E2, L2, b, voq, h, v2, f2m);
    field_split<20, 100000>(x3, E3, L3, b, voq, h, v3, f3m);
    fmv += v2[2] * v3[2];                                     // (2,3)

    field_one<1000000>(x0, E0, L0, b, voq, v0, f0m);
    fmv += v0[1] * v2[0] + v0[2] * v3[0];                     // (0,2)(0,3)

    field_one<500000>(x1, E1, L1, b, voq, v1, f1m);
    fmv += v0[0] * v1[0] + v1[1] * v2[1] + v1[2] * v3[1];     // (0,1)(1,2)(1,3)

    field_one<10000>(x4, E4, L4, b, voq, v4, f4m);
    fmv += v0[3] * v4[0] + v1[3] * v4[1]
         + v2[3] * v4[2] + v3[3] * v4[3];                     // (i,4)

    field_one<1000>(x5, E5, L5, b, voq, v5, f5m);
    fmv += v0[4] * v5[0] + v1[4] * v5[1] + v2[4] * v5[2]
         + v3[4] * v5[3] + v4[4] * v5[4];                     // (i,5)

    // sum this lane's 4 latent components, then reduce across the 4 quads
    float fm = fmv.x + fmv.y + fmv.z + fmv.w;
    fm += __shfl_xor(fm, 1, 4);
    fm += __shfl_xor(fm, 2, 4);

    if (t == 0) {
        float lin = f0m * Wd[0] + f1m * Wd[1] + f2m * Wd[2]
                  + f3m * Wd[3] + f4m * Wd[4] + f5m * Wd[5] + bd[0];
        lin = fmaxf(lin, 0.0f);
        const float z = lin + fm;
        out[b] = 1.0f / (1.0f + __expf(-z));
    }
}

extern "C" void kernel_launch(void* const* d_in, const int* in_sizes, int n_in,
                              void* d_out, int out_size, void* d_ws, size_t ws_size,
                              hipStream_t stream)
{
    const int* x0 = (const int*)d_in[0];
    const int* x1 = (const int*)d_in[1];
    const int* x2 = (const int*)d_in[2];
    const int* x3 = (const int*)d_in[3];
    const int* x4 = (const int*)d_in[4];
    const int* x5 = (const int*)d_in[5];

    const float *E0, *E1, *E2, *E3, *E4, *E5;
    const float *L0, *L1, *L2, *L3, *L4, *L5;

    // setup_inputs() dict order interleaves (E_i, L_i). Detect defensively:
    // in_sizes[7] == 1,000,000 -> interleaved (d_in[7] is L0);
    // in_sizes[7] == 40,000,000 -> grouped   (d_in[7] is E1).
    if (in_sizes[7] == 1000000) {
        E0 = (const float*)d_in[6];  L0 = (const float*)d_in[7];
        E1 = (const float*)d_in[8];  L1 = (const float*)d_in[9];
        E2 = (const float*)d_in[10]; L2 = (const float*)d_in[11];
        E3 = (const float*)d_in[12]; L3 = (const float*)d_in[13];
        E4 = (const float*)d_in[14]; L4 = (const float*)d_in[15];
        E5 = (const float*)d_in[16]; L5 = (const float*)d_in[17];
    } else {
        E0 = (const float*)d_in[6];  E1 = (const float*)d_in[7];
        E2 = (const float*)d_in[8];  E3 = (const float*)d_in[9];
        E4 = (const float*)d_in[10]; E5 = (const float*)d_in[11];
        L0 = (const float*)d_in[12]; L1 = (const float*)d_in[13];
        L2 = (const float*)d_in[14]; L3 = (const float*)d_in[15];
        L4 = (const float*)d_in[16]; L5 = (const float*)d_in[17];
    }
    const float* Wd = (const float*)d_in[18];
    const float* bd = (const float*)d_in[19];
    float* out = (float*)d_out;

    dim3 block(256);
    dim3 grid((BATCH * LATENT) / 256);   // 1024 blocks, 16 batch elements each
    hipLaunchKernelGGL(ffm_kernel, grid, block, 0, stream,
                       x0, x1, x2, x3, x4, x5,
                       E0, E1, E2, E3, E4, E5,
                       L0, L1, L2, L3, L4, L5,
                       Wd, bd, out);
}